// Round 1
// baseline (9576.157 us; speedup 1.0000x reference)
//
#include <hip/hip_runtime.h>

typedef __attribute__((ext_vector_type(8))) short short8v;
typedef __attribute__((ext_vector_type(4))) float f32x4;

#define NB 1024
#define NS 200
#define ND 512
#define NG 1536
#define NM 204800   // NB*NS
#define NFF 256

__device__ __forceinline__ float bf2f(unsigned short u){
  union { unsigned u; float f; } v; v.u = ((unsigned)u) << 16; return v.f;
}
__device__ __forceinline__ unsigned short f2bf(float f){
  union { float f; unsigned u; } v; v.f = f;
  unsigned r = v.u + 0x7fffu + ((v.u >> 16) & 1u);
  return (unsigned short)(r >> 16);
}
__device__ __forceinline__ float sigm(float x){ return 1.f / (1.f + __expf(-x)); }
__device__ __forceinline__ float tanhfast(float x){ return 1.f - 2.f / (1.f + __expf(2.f * x)); }

// ---------------- cast f32 -> bf16, 8 elements/thread ----------------
__global__ void k_cast_bf16(const float* __restrict__ in, unsigned short* __restrict__ out, size_t n8){
  size_t i = (size_t)blockIdx.x * blockDim.x + threadIdx.x;
  size_t stride = (size_t)gridDim.x * blockDim.x;
  for (; i < n8; i += stride){
    const float4* p = (const float4*)(in + i * 8);
    float4 a = p[0], b = p[1];
    uint4 v;
    v.x = (unsigned)f2bf(a.x) | ((unsigned)f2bf(a.y) << 16);
    v.y = (unsigned)f2bf(a.z) | ((unsigned)f2bf(a.w) << 16);
    v.z = (unsigned)f2bf(b.x) | ((unsigned)f2bf(b.y) << 16);
    v.w = (unsigned)f2bf(b.z) | ((unsigned)f2bf(b.w) << 16);
    *(uint4*)(out + i * 8) = v;
  }
}

// ---------------- pack W (N x K, row-major, f32) into MFMA B-frag order ----------------
// out[((ntile*16+kk)*64 + lane)*8 + j] = bf16( W[(ntile*16 + (lane&15))*ld + coloff + kk*32 + (lane>>4)*8 + j] )
__global__ void k_prepack(const float* __restrict__ W, unsigned short* __restrict__ out,
                          int ld, int coloff, int ntiles){
  int gid = blockIdx.x * 256 + threadIdx.x;
  if (gid >= ntiles * 1024) return;
  int ntile = gid >> 10; int rem = gid & 1023;
  int kk = rem >> 6; int lane = rem & 63;
  int c = ntile * 16 + (lane & 15);
  int k0 = kk * 32 + (lane >> 4) * 8;
  const float* s = W + (size_t)c * ld + coloff + k0;
  uint4 v;
  v.x = (unsigned)f2bf(s[0]) | ((unsigned)f2bf(s[1]) << 16);
  v.y = (unsigned)f2bf(s[2]) | ((unsigned)f2bf(s[3]) << 16);
  v.z = (unsigned)f2bf(s[4]) | ((unsigned)f2bf(s[5]) << 16);
  v.w = (unsigned)f2bf(s[6]) | ((unsigned)f2bf(s[7]) << 16);
  *(uint4*)(out + (size_t)gid * 8) = v;
}

// ---------------- tvec[b][f] = b_fc[f] + sum_d target[b][d] * W_fc[f][512+d] ----------------
__global__ void k_tvec(const float* __restrict__ target, const float* __restrict__ Wfc,
                       const float* __restrict__ bfc, float* __restrict__ tvec){
  __shared__ float tg[4][ND];
  int bb = blockIdx.x;          // 256 blocks, 4 b each
  int tid = threadIdx.x;        // 256 = f
  for (int idx = tid; idx < 4 * ND; idx += 256){
    int j = idx >> 9, d = idx & 511;
    tg[j][d] = target[(size_t)(bb * 4 + j) * ND + d];
  }
  __syncthreads();
  const float* wrow = Wfc + (size_t)tid * 1024 + 512;
  float a0 = 0, a1 = 0, a2 = 0, a3 = 0;
  for (int d = 0; d < ND; ++d){
    float wv = wrow[d];
    a0 += tg[0][d] * wv; a1 += tg[1][d] * wv; a2 += tg[2][d] * wv; a3 += tg[3][d] * wv;
  }
  float bias = bfc[tid];
  tvec[(size_t)(bb * 4 + 0) * NFF + tid] = a0 + bias;
  tvec[(size_t)(bb * 4 + 1) * NFF + tid] = a1 + bias;
  tvec[(size_t)(bb * 4 + 2) * NFF + tid] = a2 + bias;
  tvec[(size_t)(bb * 4 + 3) * NFF + tid] = a3 + bias;
}

// ---------------- gx = hist_bf16 @ W_ih^T + b_ih, output bf16 (NM x 1536) ----------------
// 128x128 tile, BK=64, 4 waves (2x2), B-frags direct from packed W_ih.
__global__ __launch_bounds__(256) void k_gemm_gx(const unsigned short* __restrict__ A,
                                                 const unsigned short* __restrict__ Bpk,
                                                 const float* __restrict__ bih,
                                                 unsigned short* __restrict__ gx){
  __shared__ unsigned short As[128 * 64];
  int tid = threadIdx.x; int lane = tid & 63; int wid = tid >> 6;
  int wm = wid >> 1, wn = wid & 1;
  int Nb = blockIdx.x, Mb = blockIdx.y;
  const unsigned short* Abase = A + (size_t)Mb * 128 * ND;
  const short8v* Bp = (const short8v*)Bpk;
  f32x4 acc[4][4];
  #pragma unroll
  for (int i = 0; i < 4; ++i)
    #pragma unroll
    for (int j = 0; j < 4; ++j) acc[i][j] = (f32x4){0.f, 0.f, 0.f, 0.f};

  for (int kc = 0; kc < 8; ++kc){
    __syncthreads();
    #pragma unroll
    for (int pass = 0; pass < 4; ++pass){
      int idx = pass * 256 + tid; int r = idx >> 3, ch = idx & 7;
      uint4 v = *(const uint4*)(Abase + (size_t)r * ND + kc * 64 + ch * 8);
      *(uint4*)&As[r * 64 + ch * 8] = v;
    }
    __syncthreads();
    #pragma unroll
    for (int i = 0; i < 2; ++i){
      short8v a[4];
      #pragma unroll
      for (int mt = 0; mt < 4; ++mt)
        a[mt] = *(const short8v*)&As[(wm * 64 + mt * 16 + (lane & 15)) * 64 + i * 32 + (lane >> 4) * 8];
      #pragma unroll
      for (int nt = 0; nt < 4; ++nt){
        short8v b = Bp[((size_t)(Nb * 8 + wn * 4 + nt) * 16 + (kc * 2 + i)) * 64 + lane];
        #pragma unroll
        for (int mt = 0; mt < 4; ++mt)
          acc[mt][nt] = __builtin_amdgcn_mfma_f32_16x16x32_bf16(a[mt], b, acc[mt][nt], 0, 0, 0);
      }
    }
  }
  #pragma unroll
  for (int mt = 0; mt < 4; ++mt){
    #pragma unroll
    for (int nt = 0; nt < 4; ++nt){
      int gcol = Nb * 128 + wn * 64 + nt * 16 + (lane & 15);
      float bv = bih[gcol];
      #pragma unroll
      for (int r = 0; r < 4; ++r){
        int grow = Mb * 128 + wm * 64 + mt * 16 + (lane >> 4) * 4 + r;
        gx[(size_t)grow * NG + gcol] = f2bf(acc[mt][nt][r] + bv);
      }
    }
  }
}

// ---------------- GRU recurrence: 64 blocks x 16 waves, W_hh resident in VGPRs ----------------
__global__ __launch_bounds__(1024, 4) void k_gru(const unsigned short* __restrict__ gx,
                                                 const unsigned short* __restrict__ Wpk,
                                                 const float* __restrict__ bhh,
                                                 unsigned short* __restrict__ gout){
  __shared__ unsigned short hl[16][520];   // 520 = 512 + 8 pad (16B-aligned rows, conflict-light)
  int tid = threadIdx.x; int lane = tid & 63; int w = tid >> 6;
  int bbase = blockIdx.x * 16;
  for (int i = tid; i < 16 * 520; i += 1024) ((unsigned short*)hl)[i] = 0;

  // resident W_hh fragments: wave w owns cols {g*512 + w*32 + sub*16 + (lane&15)}
  short8v wf[6][16];
  const short8v* Wp = (const short8v*)Wpk;
  #pragma unroll
  for (int nt = 0; nt < 6; ++nt){
    int g = nt >> 1, sub = nt & 1;
    int ntg = g * 32 + w * 2 + sub;
    #pragma unroll
    for (int kk = 0; kk < 16; ++kk)
      wf[nt][kk] = Wp[((size_t)ntg * 16 + kk) * 64 + lane];
  }
  float hreg[2][4];
  #pragma unroll
  for (int s = 0; s < 2; ++s)
    #pragma unroll
    for (int r = 0; r < 4; ++r) hreg[s][r] = 0.f;

  float bR[2], bZ[2], bN[2];
  #pragma unroll
  for (int sub = 0; sub < 2; ++sub){
    int c = w * 32 + sub * 16 + (lane & 15);
    bR[sub] = bhh[c]; bZ[sub] = bhh[512 + c]; bN[sub] = bhh[1024 + c];
  }
  __syncthreads();

  #pragma unroll 1
  for (int t = 0; t < NS; ++t){
    // prefetch gx_t (independent of h -> overlaps MFMA latency)
    float xr[2][4], xz[2][4], xn[2][4];
    #pragma unroll
    for (int sub = 0; sub < 2; ++sub){
      int c = w * 32 + sub * 16 + (lane & 15);
      #pragma unroll
      for (int r = 0; r < 4; ++r){
        int row = (lane >> 4) * 4 + r;
        const unsigned short* gp = gx + ((size_t)(bbase + row) * NS + t) * NG;
        xr[sub][r] = bf2f(gp[c]);
        xz[sub][r] = bf2f(gp[512 + c]);
        xn[sub][r] = bf2f(gp[1024 + c]);
      }
    }
    f32x4 acc[6];
    #pragma unroll
    for (int nt = 0; nt < 6; ++nt) acc[nt] = (f32x4){0.f, 0.f, 0.f, 0.f};
    #pragma unroll
    for (int kc = 0; kc < 8; ++kc){
      short8v a[2];
      #pragma unroll
      for (int i = 0; i < 2; ++i)
        a[i] = *(const short8v*)&hl[lane & 15][(kc * 2 + i) * 32 + (lane >> 4) * 8];
      #pragma unroll
      for (int nt = 0; nt < 6; ++nt)
        #pragma unroll
        for (int i = 0; i < 2; ++i)
          acc[nt] = __builtin_amdgcn_mfma_f32_16x16x32_bf16(a[i], wf[nt][kc * 2 + i], acc[nt], 0, 0, 0);
    }
    unsigned short hnew[2][4];
    #pragma unroll
    for (int sub = 0; sub < 2; ++sub){
      #pragma unroll
      for (int r = 0; r < 4; ++r){
        float rr = sigm(xr[sub][r] + acc[sub][r] + bR[sub]);
        float zz = sigm(xz[sub][r] + acc[2 + sub][r] + bZ[sub]);
        float nn = tanhfast(xn[sub][r] + rr * (acc[4 + sub][r] + bN[sub]));
        float h = nn + zz * (hreg[sub][r] - nn);   // (1-z)n + z h
        hreg[sub][r] = h;
        hnew[sub][r] = f2bf(h);
      }
    }
    __syncthreads();   // all waves done reading h for this step
    #pragma unroll
    for (int sub = 0; sub < 2; ++sub){
      int c = w * 32 + sub * 16 + (lane & 15);
      #pragma unroll
      for (int r = 0; r < 4; ++r){
        int row = (lane >> 4) * 4 + r;
        hl[row][c] = hnew[sub][r];
        gout[((size_t)(bbase + row) * NS + t) * ND + c] = hnew[sub][r];
      }
    }
    __syncthreads();   // h updated for next step
  }
}

// ---------------- pre/GELU/scores fused GEMM: (NM x 512) @ Wg^T (256) ----------------
__global__ __launch_bounds__(512) void k_gemm_s4(const unsigned short* __restrict__ A,
                                                 const unsigned short* __restrict__ Bpk,
                                                 const float* __restrict__ tvec,
                                                 const float* __restrict__ Wsc,
                                                 const float* __restrict__ bsc,
                                                 float* __restrict__ scores){
  __shared__ unsigned short As[128 * 64];
  __shared__ float spart[4][128];
  int tid = threadIdx.x; int lane = tid & 63; int wid = tid >> 6;
  int wm = wid >> 2, wn = wid & 3;
  int Mb = blockIdx.x;
  const unsigned short* Abase = A + (size_t)Mb * 128 * ND;
  const short8v* Bp = (const short8v*)Bpk;
  f32x4 acc[4][4];
  #pragma unroll
  for (int i = 0; i < 4; ++i)
    #pragma unroll
    for (int j = 0; j < 4; ++j) acc[i][j] = (f32x4){0.f, 0.f, 0.f, 0.f};

  for (int kc = 0; kc < 8; ++kc){
    __syncthreads();
    #pragma unroll
    for (int pass = 0; pass < 2; ++pass){
      int idx = pass * 512 + tid; int r = idx >> 3, ch = idx & 7;
      uint4 v = *(const uint4*)(Abase + (size_t)r * ND + kc * 64 + ch * 8);
      *(uint4*)&As[r * 64 + ch * 8] = v;
    }
    __syncthreads();
    #pragma unroll
    for (int i = 0; i < 2; ++i){
      short8v a[4];
      #pragma unroll
      for (int mt = 0; mt < 4; ++mt)
        a[mt] = *(const short8v*)&As[(wm * 64 + mt * 16 + (lane & 15)) * 64 + i * 32 + (lane >> 4) * 8];
      #pragma unroll
      for (int nt = 0; nt < 4; ++nt){
        short8v b = Bp[((size_t)(wn * 4 + nt) * 16 + (kc * 2 + i)) * 64 + lane];
        #pragma unroll
        for (int mt = 0; mt < 4; ++mt)
          acc[mt][nt] = __builtin_amdgcn_mfma_f32_16x16x32_bf16(a[mt], b, acc[mt][nt], 0, 0, 0);
      }
    }
  }
  // epilogue: pre = acc + tvec[b], gelu, dot with Wsc, reduce over the 16 col-lanes
  #pragma unroll
  for (int mt = 0; mt < 4; ++mt){
    #pragma unroll
    for (int r = 0; r < 4; ++r){
      int rowl = wm * 64 + mt * 16 + (lane >> 4) * 4 + r;
      unsigned grow = (unsigned)(Mb * 128 + rowl);
      unsigned bidx = grow / 200u;
      float rowsum = 0.f;
      #pragma unroll
      for (int nt = 0; nt < 4; ++nt){
        int gcol = wn * 64 + nt * 16 + (lane & 15);
        float pre = acc[mt][nt][r] + tvec[(size_t)bidx * NFF + gcol];
        float g = 0.5f * pre * (1.f + erff(pre * 0.70710678118654752f));
        rowsum += g * Wsc[gcol];
      }
      rowsum += __shfl_xor(rowsum, 1, 64);
      rowsum += __shfl_xor(rowsum, 2, 64);
      rowsum += __shfl_xor(rowsum, 4, 64);
      rowsum += __shfl_xor(rowsum, 8, 64);
      if ((lane & 15) == 0) spart[wn][rowl] = rowsum;
    }
  }
  __syncthreads();
  if (tid < 128){
    float s = spart[0][tid] + spart[1][tid] + spart[2][tid] + spart[3][tid] + bsc[0];
    scores[(size_t)Mb * 128 + tid] = s;
  }
}

// ---------------- softmax over S + weighted pool + concat output ----------------
__global__ void k_out(const float* __restrict__ scores, const unsigned short* __restrict__ gout,
                      const float* __restrict__ target, float* __restrict__ out){
  int b = blockIdx.x; int tid = threadIdx.x;
  __shared__ float sw[NS];
  __shared__ float red[4];
  float v = (tid < NS) ? scores[(size_t)b * NS + tid] : -3.0e38f;
  float m = v;
  #pragma unroll
  for (int off = 32; off >= 1; off >>= 1) m = fmaxf(m, __shfl_xor(m, off, 64));
  if ((tid & 63) == 0) red[tid >> 6] = m;
  __syncthreads();
  m = fmaxf(fmaxf(red[0], red[1]), fmaxf(red[2], red[3]));
  float e = (tid < NS) ? __expf(v - m) : 0.f;
  if (tid < NS) sw[tid] = e;
  float su = e;
  #pragma unroll
  for (int off = 32; off >= 1; off >>= 1) su += __shfl_xor(su, off, 64);
  __syncthreads();
  if ((tid & 63) == 0) red[tid >> 6] = su;
  __syncthreads();
  float inv = 1.f / (red[0] + red[1] + red[2] + red[3]);
  int d0 = tid * 2;
  float a0 = 0.f, a1 = 0.f;
  const unsigned short* gbase = gout + (size_t)b * NS * ND + d0;
  for (int s = 0; s < NS; ++s){
    unsigned u = *(const unsigned*)(gbase + (size_t)s * ND);
    float wgt = sw[s];
    a0 += wgt * bf2f((unsigned short)(u & 0xffffu));
    a1 += wgt * bf2f((unsigned short)(u >> 16));
  }
  out[(size_t)b * 1024 + d0] = a0 * inv;
  out[(size_t)b * 1024 + d0 + 1] = a1 * inv;
  float2 tv = *(const float2*)(target + (size_t)b * ND + d0);
  out[(size_t)b * 1024 + 512 + d0] = tv.x;
  out[(size_t)b * 1024 + 512 + d0 + 1] = tv.y;
}

extern "C" void kernel_launch(void* const* d_in, const int* in_sizes, int n_in,
                              void* d_out, int out_size, void* d_ws, size_t ws_size,
                              hipStream_t stream) {
  const float* target  = (const float*)d_in[0];
  const float* history = (const float*)d_in[1];
  const float* W_ih    = (const float*)d_in[2];
  const float* W_hh    = (const float*)d_in[3];
  const float* b_ih    = (const float*)d_in[4];
  const float* b_hh    = (const float*)d_in[5];
  const float* W_fc    = (const float*)d_in[6];
  const float* b_fc    = (const float*)d_in[7];
  const float* W_sc    = (const float*)d_in[8];
  const float* b_sc    = (const float*)d_in[9];

  char* ws = (char*)d_ws;
  size_t off = 0;
  unsigned short* histb  = (unsigned short*)(ws + off); off += 209715200ull;  // NM*512 bf16
  unsigned short* gx     = (unsigned short*)(ws + off); off += 629145600ull;  // NM*1536 bf16
  unsigned short* gout   = (unsigned short*)(ws + off); off += 209715200ull;  // NM*512 bf16
  unsigned short* wih_pk = (unsigned short*)(ws + off); off += 1572864ull;
  unsigned short* whh_pk = (unsigned short*)(ws + off); off += 1572864ull;
  unsigned short* wg_pk  = (unsigned short*)(ws + off); off += 262144ull;
  float*          tvec   = (float*)(ws + off);          off += 1048576ull;
  float*          scores = (float*)(ws + off);          off += 819200ull;
  if (ws_size < off) return;
  float* outp = (float*)d_out;

  k_cast_bf16<<<2048, 256, 0, stream>>>(history, histb, (size_t)13107200ull);
  k_prepack<<<384, 256, 0, stream>>>(W_ih, wih_pk, 512, 0, 96);
  k_prepack<<<384, 256, 0, stream>>>(W_hh, whh_pk, 512, 0, 96);
  k_prepack<<<64, 256, 0, stream>>>(W_fc, wg_pk, 1024, 0, 16);
  k_tvec<<<256, 256, 0, stream>>>(target, W_fc, b_fc, tvec);
  k_gemm_gx<<<dim3(12, 1600), 256, 0, stream>>>(histb, wih_pk, b_ih, gx);
  k_gru<<<64, 1024, 0, stream>>>(gx, whh_pk, b_hh, gout);
  k_gemm_s4<<<1600, 512, 0, stream>>>(gout, wg_pk, tvec, W_sc, b_sc, scores);
  k_out<<<1024, 256, 0, stream>>>(scores, gout, target, outp);
}